// Round 13
// baseline (72.789 us; speedup 1.0000x reference)
//
#include <hip/hip_runtime.h>

// patches: [N=128, C=4, P=32, P, P] fp32 ; vol/out: [B=2, C=4, 128,128,128] fp32
// centers: [N,3] int32 ; lo = center-16 (lo in [0,96]) ; patch n -> batch b = n/64
// out = 0.5*vol + 0.5*scatter(patches), computed as a GATHER (no atomics).
// R13: 2-deep software-pipelined candidate walk (ping-pong load slots, no
//      register rotation -> compiler emits counted vmcnt waits, candidate
//      i+1's loads fly while candidate i accumulates) + per-WAVE ballot
//      window (each wave spans only 2 w values -> fewer, denser candidates).
//  - channel-split mapping (R10): 1 thread = 1 channel x 4 d-voxels
//  - aligned ka/kb float4 gather + wave-uniform shift (k0&3 lane-invariant)
//  - barrier-free (R11): no LDS, no __syncthreads

constexpr int C = 4, H = 128, P = 32;
constexpr int NPB  = 64;               // patches per batch
constexpr int PCH4 = P * P * P / 4;    // patch channel stride in float4 (8192)

__global__ __launch_bounds__(256) void patch_gather_kernel(
        const float4* __restrict__ patches4,
        const int*   __restrict__ centers,
        const float4* __restrict__ vol4,
        float4* __restrict__ out4) {
    int blk = blockIdx.x;              // (((b*4 + c)*128 + h)*16 + wgrp)
    int wgrp = blk & 15;
    int h    = (blk >> 4) & 127;
    int c    = (blk >> 11) & 3;
    int b    = blk >> 13;
    int tid  = threadIdx.x;

    int w0 = wgrp << 3;                // block covers w0..w0+7
    int d4 = tid & 31;
    int w  = w0 + (tid >> 5);
    int d0 = d4 << 2;

    // ---- issue vol load EARLY ------------------------------------------
    int base4 = (((b * C + c) * H + h) * H + w) * 32 + d4;
    float4 v = vol4[base4];

    // ---- wave-autonomous filter: lane l evaluates patch l --------------
    int lane = tid & 63;
    int cb   = (b * NPB + lane) * 3;
    int lo0  = centers[cb + 0] - 16;   // in [0,96]
    int lo1  = centers[cb + 1] - 16;
    int lo2  = centers[cb + 2] - 16;
    // this wave covers exactly w-values {wlo, wlo+1}
    int wlo  = w0 + ((tid >> 6) << 1);
    bool cand = ((unsigned)(h - lo0) < 32u) &&
                ((unsigned)(wlo - lo1 + 1) < 33u);     // [wlo,wlo+1] intersect
    int packed = ((h - lo0) << 14) | (lo1 << 7) | lo2; // hi | lo1 | lo2
    unsigned long long mask = __ballot(cand);

    float4 acc = make_float4(0.f, 0.f, 0.f, 0.f);
    const float4* pbat = patches4 + ((size_t)b * NPB * C + c) * PCH4;
    const float4 z = make_float4(0.f, 0.f, 0.f, 0.f);

    // fetch: pop lowest candidate, issue its (<=2) gather loads into A/Bv
    auto fetch = [&](float4& A, float4& Bv, int& sh) {
        int l = __ffsll((long long)mask) - 1;
        mask &= mask - 1;
        int e = __shfl(packed, l);
        int hi   = (e >> 14) & 31;
        int plo1 = (e >> 7) & 127;
        int plo2 = e & 127;
        int wi = w - plo1;
        int k0 = d0 - plo2;
        bool hit = ((unsigned)wi < 32u) && (k0 > -4) && (k0 < 32);
        A = z; Bv = z;
        if (hit) {
            int q = (k0 + 4) >> 2;     // 0..8
            int ka = q - 1, kb = q;    // aligned float4 window
            const float4* pr = pbat + (size_t)l * C * PCH4 + (hi * 32 + wi) * 8;
            if ((unsigned)ka < 8u) A  = pr[ka];
            if ((unsigned)kb < 8u) Bv = pr[kb];
        }
        sh = __builtin_amdgcn_readfirstlane(k0 & 3); // lane-invariant
    };

    auto accum = [&](const float4& A, const float4& Bv, int sh) {
        switch (sh) {
        case 0:
            acc.x += A.x; acc.y += A.y; acc.z += A.z; acc.w += A.w; break;
        case 1:
            acc.x += A.y; acc.y += A.z; acc.z += A.w; acc.w += Bv.x; break;
        case 2:
            acc.x += A.z; acc.y += A.w; acc.z += Bv.x; acc.w += Bv.y; break;
        default:
            acc.x += A.w; acc.y += Bv.x; acc.z += Bv.y; acc.w += Bv.z; break;
        }
    };

    // ---- 2-deep pipelined walk: slot being accumulated never blocks the
    //      other slot's in-flight loads (ping-pong, no reg rotation) ------
    int nc = (int)__popcll(mask);
    if (nc > 0) {
        float4 A0, B0, A1, B1;
        int sh0, sh1;
        fetch(A0, B0, sh0);
        int rem = nc - 1;
        while (rem > 0) {
            fetch(A1, B1, sh1); --rem;     // issue slot1 loads
            accum(A0, B0, sh0);            // wait slot0 only
            if (rem > 0) {
                fetch(A0, B0, sh0); --rem; // issue slot0 loads
                accum(A1, B1, sh1);        // wait slot1 only
            } else {
                accum(A1, B1, sh1);
                rem = -1;                  // slot0 already consumed
            }
        }
        if (rem == 0) accum(A0, B0, sh0);  // odd count: tail slot0
    }

    // ---- epilogue: out = 0.5*(vol + acc) -------------------------------
    float4 o;
    o.x = (v.x + acc.x) * 0.5f;
    o.y = (v.y + acc.y) * 0.5f;
    o.z = (v.z + acc.z) * 0.5f;
    o.w = (v.w + acc.w) * 0.5f;
    out4[base4] = o;
}

extern "C" void kernel_launch(void* const* d_in, const int* in_sizes, int n_in,
                              void* d_out, int out_size, void* d_ws, size_t ws_size,
                              hipStream_t stream) {
    const float* patches = (const float*)d_in[0];
    const float* vol     = (const float*)d_in[1];
    const int*   centers = (const int*)d_in[2];
    float* out = (float*)d_out;

    patch_gather_kernel<<<16384, 256, 0, stream>>>(
        (const float4*)patches, centers, (const float4*)vol, (float4*)out);
}